// Round 5
// baseline (274.427 us; speedup 1.0000x reference)
//
#include <hip/hip_runtime.h>

#define NB 1024
#define NE 8

__device__ __forceinline__ float relu6f(float v) { return fminf(fmaxf(v, 0.0f), 6.0f); }

// ---------------- Kernel A: router conv + softmax ----------------
__global__ __launch_bounds__(256) void router_kernel(
    const float* __restrict__ x, const float* __restrict__ rw,
    const float* __restrict__ rb, float* __restrict__ ss)
{
    __shared__ float rw_l[384];
    __shared__ float red[4][8];
    int b = blockIdx.x, t = threadIdx.x;
    for (int i = t; i < 384; i += 256) rw_l[i] = rw[i];
    __syncthreads();
    float acc[NE];
#pragma unroll
    for (int e = 0; e < NE; ++e) acc[e] = 0.f;
    const float* xb = x + b * 3072;
    for (int idx = t; idx < 3072; idx += 256) {
        float xv = xb[idx];
        int c = idx >> 10, rem = idx & 1023;
        int i = rem >> 5, j = rem & 31;
        int wb = c * 16 + (i & 3) * 4 + (j & 3);
#pragma unroll
        for (int e = 0; e < NE; ++e) acc[e] += xv * rw_l[e * 48 + wb];
    }
#pragma unroll
    for (int off = 32; off >= 1; off >>= 1) {
#pragma unroll
        for (int e = 0; e < NE; ++e) acc[e] += __shfl_xor(acc[e], off);
    }
    int lane = t & 63, wave = t >> 6;
    if (lane == 0) {
#pragma unroll
        for (int e = 0; e < NE; ++e) red[wave][e] = acc[e];
    }
    __syncthreads();
    if (t == 0) {
        float s[NE], m = -1e30f;
#pragma unroll
        for (int e = 0; e < NE; ++e) {
            s[e] = red[0][e] + red[1][e] + red[2][e] + red[3][e] + rb[e];
            m = fmaxf(m, s[e]);
        }
        float xs = 0.f, ex[NE];
#pragma unroll
        for (int e = 0; e < NE; ++e) { ex[e] = expf(s[e] - m); xs += ex[e]; }
#pragma unroll
        for (int e = 0; e < NE; ++e) ss[b * 8 + e] = ex[e] / xs;
    }
}

// ---------------- Kernel B: OT solver — ONE WAVE, register-resident --------
// 64 lanes x 16 columns/lane. c[16][8] + k[16][8] must live in the unified
// VGPR/AGPR file: __launch_bounds__(64, 1) grants the full register budget
// (round-4 build capped at 152 VGPR and spilled both arrays to scratch ->
// 230us latency-bound; see m08/m24: ~450+ regs available at 1 wave/EU).
// Zero barriers / zero LDS in the main loop; divides -> v_rcp; exp -> v_exp.
// G_n = I8; G_m == I (off-diag d~5400 -> exp underflows), so C_eff = C - pi.
__global__ __launch_bounds__(64, 1) void solver_kernel(
    const float* __restrict__ ss_g, float* __restrict__ gate_ws,
    int* __restrict__ idx_ws, float* __restrict__ sel0,
    float* __restrict__ loss_out, float* __restrict__ mcnt_out)
{
    __shared__ float ssl[8192];          // full ss copy (32 KB)
    int l = threadIdx.x;                 // 0..63

    // stage ss -> LDS (coalesced float4), fold global max (ss > 0)
    float mx = 0.f;
    for (int i = l; i < 2048; i += 64) {
        float4 s4 = ((const float4*)ss_g)[i];
        ((float4*)ssl)[i] = s4;
        mx = fmaxf(mx, fmaxf(fmaxf(s4.x, s4.y), fmaxf(s4.z, s4.w)));
    }
#pragma unroll
    for (int off = 32; off >= 1; off >>= 1) mx = fmaxf(mx, __shfl_xor(mx, off));
    __syncthreads();

    float inv0 = __builtin_amdgcn_rcpf(mx + 1e-9f);

    // lane l owns columns col = q*64 + l
    float c[16][8], k[16][8], v[16], u[8];
#pragma unroll
    for (int q = 0; q < 16; ++q) {
        const float* p8 = &ssl[(q * 64 + l) * 8];
#pragma unroll
        for (int e = 0; e < 8; ++e) c[q][e] = -p8[e] * inv0;
        v[q] = 1.f;
    }
#pragma unroll
    for (int e = 0; e < 8; ++e) u[e] = 0.125f;   // u*k*v == pi0 == 0.125
#pragma unroll
    for (int q = 0; q < 16; ++q)
#pragma unroll
        for (int e = 0; e < 8; ++e) k[q][e] = 1.f;

    for (int outer = 0; outer < 25; ++outer) {
        // ce = c - pi (pi = u*k*v), store ce into k-slot, track max|ce|
        float lm = 0.f;
#pragma unroll
        for (int q = 0; q < 16; ++q)
#pragma unroll
            for (int e = 0; e < 8; ++e) {
                float ce = c[q][e] - u[e] * k[q][e] * v[q];
                k[q][e] = ce;
                lm = fmaxf(lm, fabsf(ce));
            }
#pragma unroll
        for (int off = 32; off >= 1; off >>= 1) lm = fmaxf(lm, __shfl_xor(lm, off));
        float scl = -10.f * __builtin_amdgcn_rcpf(lm + 1e-9f);  // -(1/sden)/LDA
#pragma unroll
        for (int q = 0; q < 16; ++q)
#pragma unroll
            for (int e = 0; e < 8; ++e) k[q][e] = __expf(k[q][e] * scl);
#pragma unroll
        for (int q = 0; q < 16; ++q) v[q] = 1.f;

        for (int it = 0; it < 6; ++it) {          // 5 full (u,v) + final u
            float p[8];
#pragma unroll
            for (int e = 0; e < 8; ++e) p[e] = 0.f;
#pragma unroll
            for (int q = 0; q < 16; ++q)
#pragma unroll
                for (int e = 0; e < 8; ++e) p[e] = fmaf(k[q][e], v[q], p[e]);
#pragma unroll
            for (int off = 32; off >= 1; off >>= 1) {
#pragma unroll
                for (int e = 0; e < 8; ++e) p[e] += __shfl_xor(p[e], off);
            }
#pragma unroll
            for (int e = 0; e < 8; ++e)
                u[e] = 128.f * __builtin_amdgcn_rcpf(p[e] + 1e-9f);
            if (it < 5) {
#pragma unroll
                for (int q = 0; q < 16; ++q) {
                    float cs = 0.f;
#pragma unroll
                    for (int e = 0; e < 8; ++e) cs = fmaf(k[q][e], u[e], cs);
                    v[q] = __builtin_amdgcn_rcpf(cs + 1e-9f);
                }
            }
        }
    }

    // ---- epilogue: argmax / gate / select0 / counts / loss ----
    float cnt[8], dp[8];
#pragma unroll
    for (int e = 0; e < 8; ++e) { cnt[e] = 0.f; dp[e] = 0.f; }
#pragma unroll
    for (int q = 0; q < 16; ++q) {
        int col = q * 64 + l;
        float pv[8];
#pragma unroll
        for (int e = 0; e < 8; ++e) pv[e] = u[e] * k[q][e] * v[q];
        int i = 0; float m = pv[0];
#pragma unroll
        for (int e = 1; e < 8; ++e) { if (pv[e] > m) { m = pv[e]; i = e; } }
        const float* p8 = &ssl[col * 8];
        float g = 0.f;
#pragma unroll
        for (int e = 0; e < 8; ++e) {
            float sv = p8[e];
            dp[e] += sv;
            if (i == e) g = sv;
        }
        float se[8];
#pragma unroll
        for (int e = 0; e < 8; ++e) {
            se[e] = (e == i && g != 0.f) ? 1.f : 0.f;
            cnt[e] += (e == i) ? 1.f : 0.f;
        }
        idx_ws[col] = i;
        gate_ws[col] = g;
        float4 s0 = make_float4(se[0], se[1], se[2], se[3]);
        float4 s1 = make_float4(se[4], se[5], se[6], se[7]);
        *(float4*)&sel0[col * 8] = s0;
        *(float4*)&sel0[col * 8 + 4] = s1;
    }
#pragma unroll
    for (int off = 32; off >= 1; off >>= 1) {
#pragma unroll
        for (int e = 0; e < 8; ++e) {
            cnt[e] += __shfl_xor(cnt[e], off);
            dp[e]  += __shfl_xor(dp[e], off);
        }
    }
    if (l == 0) {
        float loss = 0.f;
#pragma unroll
        for (int e = 0; e < 8; ++e) {
            loss += (dp[e] * (1.f / 1024.f)) * (cnt[e] * (1.f / 1024.f));
            mcnt_out[e] = cnt[e];
        }
        loss_out[0] = loss * 8.f;       // mean over 8 * E^2=64 -> sum * 8
    }
}

// ---------------- Kernel C: per-sample fused expert forward ----------------
__global__ __launch_bounds__(256) void expert_kernel(
    const float* __restrict__ x,
    const float* __restrict__ w1g, const float* __restrict__ b1g,
    const float* __restrict__ wdg, const float* __restrict__ bdg,
    const float* __restrict__ wpg, const float* __restrict__ bpg,
    const float* __restrict__ wfg, const float* __restrict__ bfg,
    const int* __restrict__ idx_ws, const float* __restrict__ gate_ws,
    float* __restrict__ out)
{
    __shared__ float xl[3][34][35];
    __shared__ float h1[4][33][33];
    __shared__ float h2[16][16][17];
    __shared__ float w1_l[432];
    __shared__ float wd_l[144];
    __shared__ float wp_l[512];
    __shared__ float wf_l[320];
    __shared__ float b1_l[16], bd_l[16], bp_l[32], bf_l[10];
    __shared__ float poolp[32][9];
    __shared__ float pooled[32];

    int b = blockIdx.x, t = threadIdx.x;
    int e = idx_ws[b];
    float gate = gate_ws[b];

    float* xz = &xl[0][0][0];
    for (int i = t; i < 3 * 34 * 35; i += 256) xz[i] = 0.f;
    for (int i = t; i < 432; i += 256) w1_l[i] = w1g[e * 432 + i];
    if (t < 144) wd_l[t] = wdg[e * 144 + t];
    for (int i = t; i < 512; i += 256) wp_l[i] = wpg[e * 512 + i];
    for (int i = t; i < 320; i += 256) wf_l[i] = wfg[e * 320 + i];
    if (t < 16) b1_l[t] = b1g[e * 16 + t];
    if (t < 16) bd_l[t] = bdg[e * 16 + t];
    if (t < 32) bp_l[t] = bpg[e * 32 + t];
    if (t < 10) bf_l[t] = bfg[e * 10 + t];
    __syncthreads();
    const float* xb = x + b * 3072;
    for (int i = t; i < 3072; i += 256) {
        int c = i >> 10, r = (i >> 5) & 31, j = i & 31;
        xl[c][r + 1][j + 1] = xb[i];
    }
    __syncthreads();

    int ocl = t >> 6;
    int rr = (t >> 1) & 31;
    int jh = t & 1;

    for (int g = 0; g < 4; ++g) {
        int oc = g * 4 + ocl;
        float acc[16];
        float bb = b1_l[oc];
#pragma unroll
        for (int kk = 0; kk < 16; ++kk) acc[kk] = bb;
#pragma unroll
        for (int c = 0; c < 3; ++c) {
#pragma unroll
            for (int di = 0; di < 3; ++di) {
                const float* xr = &xl[c][rr + di][jh * 16];
                float xreg[18];
#pragma unroll
                for (int kk = 0; kk < 18; ++kk) xreg[kk] = xr[kk];
#pragma unroll
                for (int dj = 0; dj < 3; ++dj) {
                    float w = w1_l[oc * 27 + c * 9 + di * 3 + dj];
#pragma unroll
                    for (int kk = 0; kk < 16; ++kk) acc[kk] = fmaf(xreg[kk + dj], w, acc[kk]);
                }
            }
        }
#pragma unroll
        for (int kk = 0; kk < 16; ++kk) h1[ocl][rr][jh * 16 + kk] = relu6f(acc[kk]);
        if (t < 132) { int cc = t / 33, kk = t % 33; h1[cc][32][kk] = 0.f; }
        if (t < 128) { h1[t >> 5][t & 31][32] = 0.f; }
        __syncthreads();
        int i2 = t >> 4, j2 = t & 15;
#pragma unroll
        for (int q = 0; q < 4; ++q) {
            float a = bd_l[g * 4 + q];
#pragma unroll
            for (int di = 0; di < 3; ++di) {
#pragma unroll
                for (int dj = 0; dj < 3; ++dj)
                    a = fmaf(h1[q][2 * i2 + di][2 * j2 + dj],
                             wd_l[(g * 4 + q) * 9 + di * 3 + dj], a);
            }
            h2[g * 4 + q][i2][j2] = relu6f(a);
        }
        __syncthreads();
    }

    int oc2 = t >> 3, part = t & 7;
    float psum = 0.f;
#pragma unroll
    for (int s = 0; s < 32; ++s) {
        int p = part * 32 + s;
        int i = p >> 4, j = p & 15;
        float a = bp_l[oc2];
#pragma unroll
        for (int c = 0; c < 16; ++c) a = fmaf(h2[c][i][j], wp_l[oc2 * 16 + c], a);
        psum += relu6f(a);
    }
    poolp[oc2][part] = psum;
    __syncthreads();
    if (t < 32) {
        float s2 = 0.f;
#pragma unroll
        for (int p2 = 0; p2 < 8; ++p2) s2 += poolp[t][p2];
        pooled[t] = s2 * (1.0f / 256.0f);
    }
    __syncthreads();
    if (t < 10) {
        float o = bf_l[t];
#pragma unroll
        for (int c = 0; c < 32; ++c) o = fmaf(pooled[c], wf_l[t * 32 + c], o);
        out[b * 10 + t] = gate * o;
    }
}

extern "C" void kernel_launch(void* const* d_in, const int* in_sizes, int n_in,
                              void* d_out, int out_size, void* d_ws, size_t ws_size,
                              hipStream_t stream) {
    const float* x  = (const float*)d_in[0];
    const float* rw = (const float*)d_in[1];
    const float* rb = (const float*)d_in[2];
    const float* w1 = (const float*)d_in[3];
    const float* b1 = (const float*)d_in[4];
    const float* wd = (const float*)d_in[5];
    const float* bd = (const float*)d_in[6];
    const float* wp = (const float*)d_in[7];
    const float* bp = (const float*)d_in[8];
    const float* wf = (const float*)d_in[9];
    const float* bf = (const float*)d_in[10];

    float* out  = (float*)d_out;       // [1024*10]
    float* sel0 = out + 10240;         // [1024*8]
    float* loss = out + 18432;         // [1]
    float* mcnt = out + 18433;         // [8]

    float* ws_f = (float*)d_ws;
    float* ss   = ws_f;                 // 8192 floats
    float* gate = ws_f + 8192;          // 1024 floats
    int*   idx  = (int*)(ws_f + 9216);  // 1024 ints

    router_kernel<<<dim3(NB), dim3(256), 0, stream>>>(x, rw, rb, ss);
    solver_kernel<<<dim3(1), dim3(64), 0, stream>>>(ss, gate, idx, sel0, loss, mcnt);
    expert_kernel<<<dim3(NB), dim3(256), 0, stream>>>(x, w1, b1, wd, bd, wp, bp,
                                                      wf, bf, idx, gate, out);
}

// Round 6
// 195.857 us; speedup vs baseline: 1.4012x; 1.4012x over previous
//
#include <hip/hip_runtime.h>

#define NB 1024
#define NE 8

__device__ __forceinline__ float relu6f(float v) { return fminf(fmaxf(v, 0.0f), 6.0f); }

// ---------------- Kernel A: router conv + softmax ----------------
__global__ __launch_bounds__(256) void router_kernel(
    const float* __restrict__ x, const float* __restrict__ rw,
    const float* __restrict__ rb, float* __restrict__ ss)
{
    __shared__ float rw_l[384];
    __shared__ float red[4][8];
    int b = blockIdx.x, t = threadIdx.x;
    for (int i = t; i < 384; i += 256) rw_l[i] = rw[i];
    __syncthreads();
    float acc[NE];
#pragma unroll
    for (int e = 0; e < NE; ++e) acc[e] = 0.f;
    const float* xb = x + b * 3072;
    for (int idx = t; idx < 3072; idx += 256) {
        float xv = xb[idx];
        int c = idx >> 10, rem = idx & 1023;
        int i = rem >> 5, j = rem & 31;
        int wb = c * 16 + (i & 3) * 4 + (j & 3);
#pragma unroll
        for (int e = 0; e < NE; ++e) acc[e] += xv * rw_l[e * 48 + wb];
    }
#pragma unroll
    for (int off = 32; off >= 1; off >>= 1) {
#pragma unroll
        for (int e = 0; e < NE; ++e) acc[e] += __shfl_xor(acc[e], off);
    }
    int lane = t & 63, wave = t >> 6;
    if (lane == 0) {
#pragma unroll
        for (int e = 0; e < NE; ++e) red[wave][e] = acc[e];
    }
    __syncthreads();
    if (t == 0) {
        float s[NE], m = -1e30f;
#pragma unroll
        for (int e = 0; e < NE; ++e) {
            s[e] = red[0][e] + red[1][e] + red[2][e] + red[3][e] + rb[e];
            m = fmaxf(m, s[e]);
        }
        float xs = 0.f, ex[NE];
#pragma unroll
        for (int e = 0; e < NE; ++e) { ex[e] = expf(s[e] - m); xs += ex[e]; }
#pragma unroll
        for (int e = 0; e < NE; ++e) ss[b * 8 + e] = ex[e] / xs;
    }
}

// ---------------- Kernel B: OT solver — 4 waves, 4 cols/lane ---------------
// Round-5 lesson: ~300 live floats/lane spill regardless of __launch_bounds__
// (allocator heuristic), and 1 wave has no latency hiding. Split across 4
// waves: 80 live floats/lane (no spill), 4x issue width, 1 barrier per
// Sinkhorn step via parity-double-buffered LDS partials.
// G_n = I8; G_m == I (off-diag d~5400 -> exp underflows), so C_eff = C - pi.
__global__ __launch_bounds__(256) void solver_kernel(
    const float* __restrict__ ss_g, float* __restrict__ gate_ws,
    int* __restrict__ idx_ws, float* __restrict__ sel0,
    float* __restrict__ loss_out, float* __restrict__ mcnt_out)
{
    __shared__ float ssl[8192];          // full ss copy (32 KB)
    __shared__ float red[2][4][8];       // [parity][wave][e] row-sum partials
    __shared__ float redm[2][4];         // [parity][wave] max partials
    __shared__ float cnt_sh[4][8], dp_sh[4][8];

    int t = threadIdx.x;
    int l = t & 63, w = t >> 6;

    // stage ss -> LDS (coalesced float4), fold global max (ss > 0)
    float mx = 0.f;
    for (int i = t; i < 2048; i += 256) {
        float4 s4 = ((const float4*)ss_g)[i];
        ((float4*)ssl)[i] = s4;
        mx = fmaxf(mx, fmaxf(fmaxf(s4.x, s4.y), fmaxf(s4.z, s4.w)));
    }
#pragma unroll
    for (int off = 32; off >= 1; off >>= 1) mx = fmaxf(mx, __shfl_xor(mx, off));
    if (l == 0) redm[0][w] = mx;
    __syncthreads();
    float gm = fmaxf(fmaxf(redm[0][0], redm[0][1]), fmaxf(redm[0][2], redm[0][3]));
    float inv0 = __builtin_amdgcn_rcpf(gm + 1e-9f);

    // lane state: columns col = w*256 + q*64 + l, q in [0,4)
    float c[4][8], k[4][8], v[4], u[8];
#pragma unroll
    for (int q = 0; q < 4; ++q) {
        const float* p8 = &ssl[(w * 256 + q * 64 + l) * 8];
#pragma unroll
        for (int e = 0; e < 8; ++e) c[q][e] = -p8[e] * inv0;
        v[q] = 1.f;
#pragma unroll
        for (int e = 0; e < 8; ++e) k[q][e] = 1.f;
    }
#pragma unroll
    for (int e = 0; e < 8; ++e) u[e] = 0.125f;   // u*k*v == pi0 == 0.125

    for (int outer = 0; outer < 25; ++outer) {
        int sm = (outer + 1) & 1;
        // ce = c - pi (pi = u*k*v); store ce into k-slot; track max|ce|
        float lm = 0.f;
#pragma unroll
        for (int q = 0; q < 4; ++q)
#pragma unroll
            for (int e = 0; e < 8; ++e) {
                float ce = c[q][e] - u[e] * k[q][e] * v[q];
                k[q][e] = ce;
                lm = fmaxf(lm, fabsf(ce));
            }
#pragma unroll
        for (int off = 32; off >= 1; off >>= 1) lm = fmaxf(lm, __shfl_xor(lm, off));
        if (l == 0) redm[sm][w] = lm;
        __syncthreads();
        float gmx = fmaxf(fmaxf(redm[sm][0], redm[sm][1]),
                          fmaxf(redm[sm][2], redm[sm][3]));
        float scl = -10.f * __builtin_amdgcn_rcpf(gmx + 1e-9f);  // -(1/sden)/LDA
#pragma unroll
        for (int q = 0; q < 4; ++q) {
#pragma unroll
            for (int e = 0; e < 8; ++e) k[q][e] = __expf(k[q][e] * scl);
            v[q] = 1.f;
        }

        for (int it = 0; it < 6; ++it) {          // 5 full (u,v) + final u
            int s = it & 1;
            float p[8];
#pragma unroll
            for (int e = 0; e < 8; ++e) p[e] = 0.f;
#pragma unroll
            for (int q = 0; q < 4; ++q)
#pragma unroll
                for (int e = 0; e < 8; ++e) p[e] = fmaf(k[q][e], v[q], p[e]);
#pragma unroll
            for (int off = 32; off >= 1; off >>= 1) {
#pragma unroll
                for (int e = 0; e < 8; ++e) p[e] += __shfl_xor(p[e], off);
            }
            if (l == 0) {
#pragma unroll
                for (int e = 0; e < 8; ++e) red[s][w][e] = p[e];
            }
            __syncthreads();
#pragma unroll
            for (int e = 0; e < 8; ++e) {
                float tot = red[s][0][e] + red[s][1][e] + red[s][2][e] + red[s][3][e];
                u[e] = 128.f * __builtin_amdgcn_rcpf(tot + 1e-9f);
            }
            if (it < 5) {
#pragma unroll
                for (int q = 0; q < 4; ++q) {
                    float cs = 0.f;
#pragma unroll
                    for (int e = 0; e < 8; ++e) cs = fmaf(k[q][e], u[e], cs);
                    v[q] = __builtin_amdgcn_rcpf(cs + 1e-9f);
                }
            }
        }
    }

    // ---- epilogue: argmax / gate / select0 / counts / loss ----
    float cnt[8], dp[8];
#pragma unroll
    for (int e = 0; e < 8; ++e) { cnt[e] = 0.f; dp[e] = 0.f; }
#pragma unroll
    for (int q = 0; q < 4; ++q) {
        int col = w * 256 + q * 64 + l;
        float pv[8];
#pragma unroll
        for (int e = 0; e < 8; ++e) pv[e] = u[e] * k[q][e] * v[q];
        int i = 0; float m = pv[0];
#pragma unroll
        for (int e = 1; e < 8; ++e) { if (pv[e] > m) { m = pv[e]; i = e; } }
        const float* p8 = &ssl[col * 8];
        float g = 0.f;
#pragma unroll
        for (int e = 0; e < 8; ++e) {
            float sv = p8[e];
            dp[e] += sv;
            if (i == e) g = sv;
        }
        float se[8];
#pragma unroll
        for (int e = 0; e < 8; ++e) {
            se[e] = (e == i && g != 0.f) ? 1.f : 0.f;
            cnt[e] += (e == i) ? 1.f : 0.f;
        }
        idx_ws[col] = i;
        gate_ws[col] = g;
        *(float4*)&sel0[col * 8]     = make_float4(se[0], se[1], se[2], se[3]);
        *(float4*)&sel0[col * 8 + 4] = make_float4(se[4], se[5], se[6], se[7]);
    }
#pragma unroll
    for (int off = 32; off >= 1; off >>= 1) {
#pragma unroll
        for (int e = 0; e < 8; ++e) {
            cnt[e] += __shfl_xor(cnt[e], off);
            dp[e]  += __shfl_xor(dp[e], off);
        }
    }
    if (l == 0) {
#pragma unroll
        for (int e = 0; e < 8; ++e) { cnt_sh[w][e] = cnt[e]; dp_sh[w][e] = dp[e]; }
    }
    __syncthreads();
    if (t == 0) {
        float loss = 0.f;
#pragma unroll
        for (int e = 0; e < 8; ++e) {
            float ce2 = cnt_sh[0][e] + cnt_sh[1][e] + cnt_sh[2][e] + cnt_sh[3][e];
            float de2 = dp_sh[0][e] + dp_sh[1][e] + dp_sh[2][e] + dp_sh[3][e];
            loss += (de2 * (1.f / 1024.f)) * (ce2 * (1.f / 1024.f));
            mcnt_out[e] = ce2;
        }
        loss_out[0] = loss * 8.f;       // mean over 8 * E^2=64 -> sum * 8
    }
}

// ---------------- Kernel C: per-sample fused expert forward ----------------
__global__ __launch_bounds__(256) void expert_kernel(
    const float* __restrict__ x,
    const float* __restrict__ w1g, const float* __restrict__ b1g,
    const float* __restrict__ wdg, const float* __restrict__ bdg,
    const float* __restrict__ wpg, const float* __restrict__ bpg,
    const float* __restrict__ wfg, const float* __restrict__ bfg,
    const int* __restrict__ idx_ws, const float* __restrict__ gate_ws,
    float* __restrict__ out)
{
    __shared__ float xl[3][34][35];
    __shared__ float h1[4][33][33];
    __shared__ float h2[16][16][17];
    __shared__ float w1_l[432];
    __shared__ float wd_l[144];
    __shared__ float wp_l[512];
    __shared__ float wf_l[320];
    __shared__ float b1_l[16], bd_l[16], bp_l[32], bf_l[10];
    __shared__ float poolp[32][9];
    __shared__ float pooled[32];

    int b = blockIdx.x, t = threadIdx.x;
    int e = idx_ws[b];
    float gate = gate_ws[b];

    float* xz = &xl[0][0][0];
    for (int i = t; i < 3 * 34 * 35; i += 256) xz[i] = 0.f;
    for (int i = t; i < 432; i += 256) w1_l[i] = w1g[e * 432 + i];
    if (t < 144) wd_l[t] = wdg[e * 144 + t];
    for (int i = t; i < 512; i += 256) wp_l[i] = wpg[e * 512 + i];
    for (int i = t; i < 320; i += 256) wf_l[i] = wfg[e * 320 + i];
    if (t < 16) b1_l[t] = b1g[e * 16 + t];
    if (t < 16) bd_l[t] = bdg[e * 16 + t];
    if (t < 32) bp_l[t] = bpg[e * 32 + t];
    if (t < 10) bf_l[t] = bfg[e * 10 + t];
    __syncthreads();
    const float* xb = x + b * 3072;
    for (int i = t; i < 3072; i += 256) {
        int c = i >> 10, r = (i >> 5) & 31, j = i & 31;
        xl[c][r + 1][j + 1] = xb[i];
    }
    __syncthreads();

    int ocl = t >> 6;
    int rr = (t >> 1) & 31;
    int jh = t & 1;

    for (int g = 0; g < 4; ++g) {
        int oc = g * 4 + ocl;
        float acc[16];
        float bb = b1_l[oc];
#pragma unroll
        for (int kk = 0; kk < 16; ++kk) acc[kk] = bb;
#pragma unroll
        for (int c = 0; c < 3; ++c) {
#pragma unroll
            for (int di = 0; di < 3; ++di) {
                const float* xr = &xl[c][rr + di][jh * 16];
                float xreg[18];
#pragma unroll
                for (int kk = 0; kk < 18; ++kk) xreg[kk] = xr[kk];
#pragma unroll
                for (int dj = 0; dj < 3; ++dj) {
                    float w = w1_l[oc * 27 + c * 9 + di * 3 + dj];
#pragma unroll
                    for (int kk = 0; kk < 16; ++kk) acc[kk] = fmaf(xreg[kk + dj], w, acc[kk]);
                }
            }
        }
#pragma unroll
        for (int kk = 0; kk < 16; ++kk) h1[ocl][rr][jh * 16 + kk] = relu6f(acc[kk]);
        if (t < 132) { int cc = t / 33, kk = t % 33; h1[cc][32][kk] = 0.f; }
        if (t < 128) { h1[t >> 5][t & 31][32] = 0.f; }
        __syncthreads();
        int i2 = t >> 4, j2 = t & 15;
#pragma unroll
        for (int q = 0; q < 4; ++q) {
            float a = bd_l[g * 4 + q];
#pragma unroll
            for (int di = 0; di < 3; ++di) {
#pragma unroll
                for (int dj = 0; dj < 3; ++dj)
                    a = fmaf(h1[q][2 * i2 + di][2 * j2 + dj],
                             wd_l[(g * 4 + q) * 9 + di * 3 + dj], a);
            }
            h2[g * 4 + q][i2][j2] = relu6f(a);
        }
        __syncthreads();
    }

    int oc2 = t >> 3, part = t & 7;
    float psum = 0.f;
#pragma unroll
    for (int s = 0; s < 32; ++s) {
        int p = part * 32 + s;
        int i = p >> 4, j = p & 15;
        float a = bp_l[oc2];
#pragma unroll
        for (int c = 0; c < 16; ++c) a = fmaf(h2[c][i][j], wp_l[oc2 * 16 + c], a);
        psum += relu6f(a);
    }
    poolp[oc2][part] = psum;
    __syncthreads();
    if (t < 32) {
        float s2 = 0.f;
#pragma unroll
        for (int p2 = 0; p2 < 8; ++p2) s2 += poolp[t][p2];
        pooled[t] = s2 * (1.0f / 256.0f);
    }
    __syncthreads();
    if (t < 10) {
        float o = bf_l[t];
#pragma unroll
        for (int c = 0; c < 32; ++c) o = fmaf(pooled[c], wf_l[t * 32 + c], o);
        out[b * 10 + t] = gate * o;
    }
}

extern "C" void kernel_launch(void* const* d_in, const int* in_sizes, int n_in,
                              void* d_out, int out_size, void* d_ws, size_t ws_size,
                              hipStream_t stream) {
    const float* x  = (const float*)d_in[0];
    const float* rw = (const float*)d_in[1];
    const float* rb = (const float*)d_in[2];
    const float* w1 = (const float*)d_in[3];
    const float* b1 = (const float*)d_in[4];
    const float* wd = (const float*)d_in[5];
    const float* bd = (const float*)d_in[6];
    const float* wp = (const float*)d_in[7];
    const float* bp = (const float*)d_in[8];
    const float* wf = (const float*)d_in[9];
    const float* bf = (const float*)d_in[10];

    float* out  = (float*)d_out;       // [1024*10]
    float* sel0 = out + 10240;         // [1024*8]
    float* loss = out + 18432;         // [1]
    float* mcnt = out + 18433;         // [8]

    float* ws_f = (float*)d_ws;
    float* ss   = ws_f;                 // 8192 floats
    float* gate = ws_f + 8192;          // 1024 floats
    int*   idx  = (int*)(ws_f + 9216);  // 1024 ints

    router_kernel<<<dim3(NB), dim3(256), 0, stream>>>(x, rw, rb, ss);
    solver_kernel<<<dim3(1), dim3(256), 0, stream>>>(ss, gate, idx, sel0, loss, mcnt);
    expert_kernel<<<dim3(NB), dim3(256), 0, stream>>>(x, w1, b1, wd, bd, wp, bp,
                                                      wf, bf, idx, gate, out);
}